// Round 5
// baseline (218.715 us; speedup 1.0000x reference)
//
#include <hip/hip_runtime.h>
#include <hip/hip_bf16.h>

#define SEQ 512
#define NE  192
#define DI  384
#define DS  384
#define DTR 12
#define NC  16      // chunks
#define LC  32      // SEQ / NC

#if __has_builtin(__builtin_amdgcn_exp2f)
#define EXP2F(x) __builtin_amdgcn_exp2f(x)
#else
#define EXP2F(x) __expf((x) * 0.69314718056f)
#endif
#define LOG2E 1.44269504089f

__device__ __forceinline__ float fast_sigmoid(float x) {
    return 1.0f / (1.0f + __expf(-x));
}

// DPP add: x + shifted(x); invalid lanes contribute 0.
template<int CTRL>
__device__ __forceinline__ float dpp_add(float x) {
    int v = __builtin_amdgcn_update_dpp(0, __float_as_int(x), CTRL, 0xf, 0xf, false);
    return x + __int_as_float(v);
}
// 4-step row reduction: lanes 15/31/47/63 hold their 16-lane row sums.
__device__ __forceinline__ float row_reduce16(float p) {
    p = dpp_add<0x111>(p);  // row_shr:1
    p = dpp_add<0x112>(p);  // row_shr:2
    p = dpp_add<0x114>(p);  // row_shr:4
    p = dpp_add<0x118>(p);  // row_shr:8
    return p;
}

// ---------------------------------------------------------------------------
// prep: Wd[n][k] = sum_r W_dt[n][r] * W_xp[r][k]   (384x384, K=12)
// ---------------------------------------------------------------------------
__launch_bounds__(DI)
__global__ void prep_wd(const float* __restrict__ W_dt, const float* __restrict__ W_xp,
                        float* __restrict__ Wd) {
    const int n = blockIdx.x;
    const int k = threadIdx.x;
    float acc = 0.0f;
    #pragma unroll
    for (int r = 0; r < DTR; ++r)
        acc = fmaf(W_dt[n * DTR + r], W_xp[r * DI + k], acc);
    Wd[(size_t)n * DI + k] = acc;
}

// ---------------------------------------------------------------------------
// Tiled fp32 GEMM:  OUT = A (MxK) @ B^T (NxK) [+bias]
// 64x64 tile, BK=32, 256 threads, register-prefetch double buffering,
// transposed LDS so fragments are ds_read_b128.
// ---------------------------------------------------------------------------
template<int MODE>
__launch_bounds__(256)
__global__ void gemm_nt(const float* __restrict__ A,
                        const float* __restrict__ Bsrc0,
                        const float* __restrict__ Bsrc1,
                        const float* __restrict__ bias,
                        float* __restrict__ O0, float* __restrict__ O1, float* __restrict__ O2,
                        int M, int N, int K) {
    __shared__ float Asm[32][68];
    __shared__ float Bsm[32][68];
    const int tid = threadIdx.x;
    const int m0 = blockIdx.y * 64;
    const int n0 = blockIdx.x * 64;
    const int tx = tid & 15;
    const int ty = tid >> 4;
    const int r  = tid >> 5;
    const int c  = tid & 31;

    float regA[8], regB[8];
    const int NK = K >> 5;

    auto load_regs = [&](int kk) {
        #pragma unroll
        for (int i = 0; i < 8; ++i) {
            const int mr = r + i * 8;
            regA[i] = A[(size_t)(m0 + mr) * K + kk + c];
            const int nr = n0 + r + i * 8;
            const float* brow = (MODE == 1 && nr >= DI)
                              ? (Bsrc1 + (size_t)(nr - DI + DTR) * K)
                              : (Bsrc0 + (size_t)nr * K);
            regB[i] = brow[kk + c];
        }
    };

    float acc[4][4];
    #pragma unroll
    for (int i = 0; i < 4; ++i)
        #pragma unroll
        for (int j = 0; j < 4; ++j) acc[i][j] = 0.0f;

    load_regs(0);
    for (int it = 0; it < NK; ++it) {
        if (it > 0) __syncthreads();
        #pragma unroll
        for (int i = 0; i < 8; ++i) {
            Asm[c][r + i * 8] = regA[i];
            Bsm[c][r + i * 8] = regB[i];
        }
        __syncthreads();
        if (it + 1 < NK) load_regs((it + 1) << 5);
        #pragma unroll
        for (int k = 0; k < 32; ++k) {
            const float4 av = *(const float4*)&Asm[k][ty * 4];
            const float4 bv = *(const float4*)&Bsm[k][tx * 4];
            acc[0][0] = fmaf(av.x, bv.x, acc[0][0]);
            acc[0][1] = fmaf(av.x, bv.y, acc[0][1]);
            acc[0][2] = fmaf(av.x, bv.z, acc[0][2]);
            acc[0][3] = fmaf(av.x, bv.w, acc[0][3]);
            acc[1][0] = fmaf(av.y, bv.x, acc[1][0]);
            acc[1][1] = fmaf(av.y, bv.y, acc[1][1]);
            acc[1][2] = fmaf(av.y, bv.z, acc[1][2]);
            acc[1][3] = fmaf(av.y, bv.w, acc[1][3]);
            acc[2][0] = fmaf(av.z, bv.x, acc[2][0]);
            acc[2][1] = fmaf(av.z, bv.y, acc[2][1]);
            acc[2][2] = fmaf(av.z, bv.z, acc[2][2]);
            acc[2][3] = fmaf(av.z, bv.w, acc[2][3]);
            acc[3][0] = fmaf(av.w, bv.x, acc[3][0]);
            acc[3][1] = fmaf(av.w, bv.y, acc[3][1]);
            acc[3][2] = fmaf(av.w, bv.z, acc[3][2]);
            acc[3][3] = fmaf(av.w, bv.w, acc[3][3]);
        }
    }

    #pragma unroll
    for (int i = 0; i < 4; ++i) {
        const int gm = m0 + ty * 4 + i;
        #pragma unroll
        for (int j = 0; j < 4; ++j) {
            const int gn = n0 + tx * 4 + j;
            float v = acc[i][j] + (bias ? bias[gn] : 0.0f);
            if (MODE == 0) {
                if (gn < DI) O0[(size_t)gm * DI + gn] = v;
                else         O1[(size_t)gm * DI + (gn - DI)] = v * fast_sigmoid(v);
            } else if (MODE == 1) {
                if (gn < DI) {
                    float sp = (v > 20.0f) ? v : log1pf(__expf(v));
                    O0[(size_t)gm * DI + gn] = sp;               // delta
                } else if (gn < 2 * DI) {
                    O1[(size_t)gm * DS + (gn - DI)] = v;         // B
                } else {
                    O2[(size_t)gm * DS + (gn - 2 * DI)] = v;     // C
                }
            } else {
                O0[(size_t)gm * NE + gn] = v;
            }
        }
    }
}

// ---------------------------------------------------------------------------
__global__ void conv_silu_kernel(const float* __restrict__ xi,
                                 const float* __restrict__ conv_w,
                                 const float* __restrict__ conv_b,
                                 float* __restrict__ u) {
    const int idx = blockIdx.x * blockDim.x + threadIdx.x;
    if (idx >= SEQ * DI) return;
    const int l = idx / DI;
    const int d = idx - l * DI;
    const float4 w = ((const float4*)conv_w)[d];
    float acc = conv_b[d];
    if (l >= 3) acc = fmaf(xi[(size_t)(l - 3) * DI + d], w.x, acc);
    if (l >= 2) acc = fmaf(xi[(size_t)(l - 2) * DI + d], w.y, acc);
    if (l >= 1) acc = fmaf(xi[(size_t)(l - 1) * DI + d], w.z, acc);
    acc = fmaf(xi[(size_t)l * DI + d], w.w, acc);
    u[idx] = acc * fast_sigmoid(acc);
}

// ---------------------------------------------------------------------------
// Phase A: chunk-local scan. Block = (chunk k, channel d), 192 threads,
// each lane owns TWO states n = 2*tid, 2*tid+1 (float2 B/C loads).
// Staged s_dtu = (dt, dt*u); Schunk computed in epilogue, not per-iter.
// ---------------------------------------------------------------------------
__launch_bounds__(192)
__global__ void scanA_kernel(const float* __restrict__ delta,
                             const float* __restrict__ u,
                             const float* __restrict__ Bmat,
                             const float* __restrict__ Cmat,
                             const float* __restrict__ A_log,
                             float* __restrict__ ylocal,
                             float* __restrict__ hend,
                             float* __restrict__ Schunk) {
    const int k    = blockIdx.x;
    const int d    = blockIdx.y;
    const int tid  = threadIdx.x;
    const int lane = tid & 63;
    const int w    = tid >> 6;      // 0..2
    const int n0   = tid * 2;
    const int l0   = k * LC;

    __shared__ float2 s_dtu[LC];    // (dt, dt*u)
    __shared__ float  part[12][LC + 1];

    if (tid < LC) {
        const float dt = delta[(size_t)(l0 + tid) * DI + d];
        const float uu = u[(size_t)(l0 + tid) * DI + d];
        s_dtu[tid] = make_float2(dt, dt * uu);
    }
    __syncthreads();

    const float2 al = *(const float2*)&A_log[(size_t)d * DS + n0];
    const float a0 = -__expf(al.x) * LOG2E;
    const float a1 = -__expf(al.y) * LOG2E;
    float h0 = 0.0f, h1 = 0.0f;

    const float2* __restrict__ bp = (const float2*)(Bmat + (size_t)l0 * DS) + tid;
    const float2* __restrict__ cp = (const float2*)(Cmat + (size_t)l0 * DS) + tid;

    #pragma unroll 4
    for (int l = 0; l < LC; ++l) {
        const float2 dtu = s_dtu[l];
        const float2 b = bp[(size_t)l * (DS / 2)];
        const float2 c = cp[(size_t)l * (DS / 2)];
        h0 = fmaf(EXP2F(dtu.x * a0), h0, dtu.y * b.x);
        h1 = fmaf(EXP2F(dtu.x * a1), h1, dtu.y * b.y);
        float p = fmaf(h1, c.y, h0 * c.x);
        p = row_reduce16(p);
        if ((lane & 15) == 15) part[(w << 2) | (lane >> 4)][l] = p;
    }

    *(float2*)&hend[(size_t)(d * NC + k) * DS + n0] = make_float2(h0, h1);
    __syncthreads();

    if (tid < LC) {
        float y = 0.0f;
        #pragma unroll
        for (int r = 0; r < 12; ++r) y += part[r][tid];
        ylocal[(size_t)d * SEQ + l0 + tid] = y;
    }
    if (tid == 192 - 1) {
        float S = 0.0f;
        #pragma unroll
        for (int l = 0; l < LC; ++l) S += s_dtu[l].x;
        Schunk[d * NC + k] = S;
    }
}

// ---------------------------------------------------------------------------
// Phase C (with fused cross-chunk combine): block = (chunk k, channel d).
// Reconstructs h_start for chunk k from hend[d,0..k-1,:] and Schunk, then
// runs the correction sweep and the gating epilogue.
// ---------------------------------------------------------------------------
__launch_bounds__(192)
__global__ void scanC_kernel(const float* __restrict__ delta,
                             const float* __restrict__ u,
                             const float* __restrict__ Cmat,
                             const float* __restrict__ A_log,
                             const float* __restrict__ Dvec,
                             const float* __restrict__ sres,
                             const float* __restrict__ ylocal,
                             const float* __restrict__ hend,
                             const float* __restrict__ Schunk,
                             float* __restrict__ yfin) {
    const int k    = blockIdx.x;
    const int d    = blockIdx.y;
    const int tid  = threadIdx.x;
    const int lane = tid & 63;
    const int w    = tid >> 6;
    const int n0   = tid * 2;
    const int l0   = k * LC;

    __shared__ float s_dt[LC];
    __shared__ float part[12][LC + 1];

    if (k > 0) {
        if (tid < LC) s_dt[tid] = delta[(size_t)(l0 + tid) * DI + d];
        __syncthreads();

        const float2 al = *(const float2*)&A_log[(size_t)d * DS + n0];
        const float a0 = -__expf(al.x) * LOG2E;
        const float a1 = -__expf(al.y) * LOG2E;

        // combine: h_start = sum_{j<k} (prod_{j<m<k} exp(a*S_m)) hend_j
        float q0 = 0.0f, q1 = 0.0f;
        for (int j = 0; j < k; ++j) {
            const float S = Schunk[d * NC + j];
            const float2 he = *(const float2*)&hend[(size_t)(d * NC + j) * DS + n0];
            q0 = fmaf(EXP2F(a0 * S), q0, he.x);
            q1 = fmaf(EXP2F(a1 * S), q1, he.y);
        }

        const float2* __restrict__ cp = (const float2*)(Cmat + (size_t)l0 * DS) + tid;

        #pragma unroll 4
        for (int l = 0; l < LC; ++l) {
            const float dt = s_dt[l];
            q0 *= EXP2F(dt * a0);
            q1 *= EXP2F(dt * a1);
            const float2 c = cp[(size_t)l * (DS / 2)];
            float p = fmaf(q1, c.y, q0 * c.x);
            p = row_reduce16(p);
            if ((lane & 15) == 15) part[(w << 2) | (lane >> 4)][l] = p;
        }
        __syncthreads();
    }

    if (tid < LC) {
        const int l = l0 + tid;
        float y = ylocal[(size_t)d * SEQ + l];
        if (k > 0) {
            #pragma unroll
            for (int r = 0; r < 12; ++r) y += part[r][tid];
        }
        const float uv = u[(size_t)l * DI + d];
        const float sr = sres[(size_t)l * DI + d];
        yfin[(size_t)l * DI + d] = (y + uv * Dvec[d]) * sr;
    }
}

// ---------------------------------------------------------------------------
extern "C" void kernel_launch(void* const* d_in, const int* in_sizes, int n_in,
                              void* d_out, int out_size, void* d_ws, size_t ws_size,
                              hipStream_t stream) {
    const float* x      = (const float*)d_in[0];
    const float* W_in   = (const float*)d_in[1];
    const float* b_in   = (const float*)d_in[2];
    const float* conv_w = (const float*)d_in[3];
    const float* conv_b = (const float*)d_in[4];
    const float* W_xp   = (const float*)d_in[5];
    const float* W_dt   = (const float*)d_in[6];
    const float* A_log  = (const float*)d_in[7];
    const float* Dvec   = (const float*)d_in[8];
    const float* W_out  = (const float*)d_in[9];
    const float* b_out  = (const float*)d_in[10];
    float* out = (float*)d_out;

    float* ws = (float*)d_ws;
    const size_t LD = (size_t)SEQ * DI;   // 196608
    float* xi     = ws;                   // dead after conv -> reused as ylocal
    float* sres   = ws + LD;
    float* u      = ws + 2 * LD;
    float* Bm     = ws + 3 * LD;
    float* Cm     = ws + 4 * LD;
    float* delta  = ws + 5 * LD;
    float* yfin   = ws + 6 * LD;
    float* ylocal = xi;                   // alias: [DI][SEQ]
    float* hend   = ws + 7 * LD;                    // [DI][NC][DS]
    float* Schunk = hend + (size_t)DI * NC * DS;    // [DI][NC]
    float* Wd     = Schunk + (size_t)DI * NC;       // [DI][DI]

    prep_wd<<<DI, DI, 0, stream>>>(W_dt, W_xp, Wd);
    gemm_nt<0><<<dim3(12, 8), 256, 0, stream>>>(x, W_in, nullptr, b_in,
                                                xi, sres, nullptr, SEQ, 2 * DI, NE);
    conv_silu_kernel<<<(SEQ * DI + 255) / 256, 256, 0, stream>>>(xi, conv_w, conv_b, u);
    gemm_nt<1><<<dim3(18, 8), 256, 0, stream>>>(u, Wd, W_xp, nullptr,
                                                delta, Bm, Cm, SEQ, 3 * DI, DI);
    scanA_kernel<<<dim3(NC, DI), 192, 0, stream>>>(delta, u, Bm, Cm, A_log,
                                                   ylocal, hend, Schunk);
    scanC_kernel<<<dim3(NC, DI), 192, 0, stream>>>(delta, u, Cm, A_log, Dvec, sres,
                                                   ylocal, hend, Schunk, yfin);
    gemm_nt<2><<<dim3(3, 8), 256, 0, stream>>>(yfin, W_out, nullptr, b_out,
                                               out, nullptr, nullptr, SEQ, NE, DI);
}

// Round 6
// 196.521 us; speedup vs baseline: 1.1129x; 1.1129x over previous
//
#include <hip/hip_runtime.h>
#include <hip/hip_bf16.h>

#define SEQ 512
#define NE  192
#define DI  384
#define DS  384
#define DTR 12
#define NC  16      // chunks
#define LC  32      // SEQ / NC
#define DG  4       // channels (d) per scan block
#define SN  6       // states per lane (6*64 = 384 = DS)

#if __has_builtin(__builtin_amdgcn_exp2f)
#define EXP2F(x) __builtin_amdgcn_exp2f(x)
#else
#define EXP2F(x) __expf((x) * 0.69314718056f)
#endif
#define LOG2E 1.44269504089f

__device__ __forceinline__ float fast_sigmoid(float x) {
    return 1.0f / (1.0f + __expf(-x));
}

// DPP add: x + shifted(x); invalid lanes contribute 0 (old = 0, bound_ctrl false).
template<int CTRL>
__device__ __forceinline__ float dpp_add(float x) {
    int v = __builtin_amdgcn_update_dpp(0, __float_as_int(x), CTRL, 0xf, 0xf, false);
    return x + __int_as_float(v);
}
// full 64-lane sum -> lane 63
__device__ __forceinline__ float wave_reduce63(float p) {
    p = dpp_add<0x111>(p);  // row_shr:1
    p = dpp_add<0x112>(p);  // row_shr:2
    p = dpp_add<0x114>(p);  // row_shr:4
    p = dpp_add<0x118>(p);  // row_shr:8
    p = dpp_add<0x142>(p);  // row_bcast:15
    p = dpp_add<0x143>(p);  // row_bcast:31
    return p;
}

// ---------------------------------------------------------------------------
// prep: Wd[n][k] = sum_r W_dt[n][r] * W_xp[r][k]   (384x384, K=12)
// ---------------------------------------------------------------------------
__launch_bounds__(DI)
__global__ void prep_wd(const float* __restrict__ W_dt, const float* __restrict__ W_xp,
                        float* __restrict__ Wd) {
    const int n = blockIdx.x;
    const int k = threadIdx.x;
    float acc = 0.0f;
    #pragma unroll
    for (int r = 0; r < DTR; ++r)
        acc = fmaf(W_dt[n * DTR + r], W_xp[r * DI + k], acc);
    Wd[(size_t)n * DI + k] = acc;
}

// ---------------------------------------------------------------------------
// Tiled fp32 GEMM:  OUT = A (MxK) @ B^T (NxK) [+bias]
// ---------------------------------------------------------------------------
template<int MODE>
__launch_bounds__(256)
__global__ void gemm_nt(const float* __restrict__ A,
                        const float* __restrict__ Bsrc0,
                        const float* __restrict__ Bsrc1,
                        const float* __restrict__ bias,
                        float* __restrict__ O0, float* __restrict__ O1, float* __restrict__ O2,
                        int M, int N, int K) {
    __shared__ float Asm[32][68];
    __shared__ float Bsm[32][68];
    const int tid = threadIdx.x;
    const int m0 = blockIdx.y * 64;
    const int n0 = blockIdx.x * 64;
    const int tx = tid & 15;
    const int ty = tid >> 4;
    const int r  = tid >> 5;
    const int c  = tid & 31;

    float regA[8], regB[8];
    const int NK = K >> 5;

    auto load_regs = [&](int kk) {
        #pragma unroll
        for (int i = 0; i < 8; ++i) {
            const int mr = r + i * 8;
            regA[i] = A[(size_t)(m0 + mr) * K + kk + c];
            const int nr = n0 + r + i * 8;
            const float* brow = (MODE == 1 && nr >= DI)
                              ? (Bsrc1 + (size_t)(nr - DI + DTR) * K)
                              : (Bsrc0 + (size_t)nr * K);
            regB[i] = brow[kk + c];
        }
    };

    float acc[4][4];
    #pragma unroll
    for (int i = 0; i < 4; ++i)
        #pragma unroll
        for (int j = 0; j < 4; ++j) acc[i][j] = 0.0f;

    load_regs(0);
    for (int it = 0; it < NK; ++it) {
        if (it > 0) __syncthreads();
        #pragma unroll
        for (int i = 0; i < 8; ++i) {
            Asm[c][r + i * 8] = regA[i];
            Bsm[c][r + i * 8] = regB[i];
        }
        __syncthreads();
        if (it + 1 < NK) load_regs((it + 1) << 5);
        #pragma unroll
        for (int k = 0; k < 32; ++k) {
            const float4 av = *(const float4*)&Asm[k][ty * 4];
            const float4 bv = *(const float4*)&Bsm[k][tx * 4];
            acc[0][0] = fmaf(av.x, bv.x, acc[0][0]);
            acc[0][1] = fmaf(av.x, bv.y, acc[0][1]);
            acc[0][2] = fmaf(av.x, bv.z, acc[0][2]);
            acc[0][3] = fmaf(av.x, bv.w, acc[0][3]);
            acc[1][0] = fmaf(av.y, bv.x, acc[1][0]);
            acc[1][1] = fmaf(av.y, bv.y, acc[1][1]);
            acc[1][2] = fmaf(av.y, bv.z, acc[1][2]);
            acc[1][3] = fmaf(av.y, bv.w, acc[1][3]);
            acc[2][0] = fmaf(av.z, bv.x, acc[2][0]);
            acc[2][1] = fmaf(av.z, bv.y, acc[2][1]);
            acc[2][2] = fmaf(av.z, bv.z, acc[2][2]);
            acc[2][3] = fmaf(av.z, bv.w, acc[2][3]);
            acc[3][0] = fmaf(av.w, bv.x, acc[3][0]);
            acc[3][1] = fmaf(av.w, bv.y, acc[3][1]);
            acc[3][2] = fmaf(av.w, bv.z, acc[3][2]);
            acc[3][3] = fmaf(av.w, bv.w, acc[3][3]);
        }
    }

    #pragma unroll
    for (int i = 0; i < 4; ++i) {
        const int gm = m0 + ty * 4 + i;
        #pragma unroll
        for (int j = 0; j < 4; ++j) {
            const int gn = n0 + tx * 4 + j;
            float v = acc[i][j] + (bias ? bias[gn] : 0.0f);
            if (MODE == 0) {
                if (gn < DI) O0[(size_t)gm * DI + gn] = v;
                else         O1[(size_t)gm * DI + (gn - DI)] = v * fast_sigmoid(v);
            } else if (MODE == 1) {
                if (gn < DI) {
                    float sp = (v > 20.0f) ? v : log1pf(__expf(v));
                    O0[(size_t)gm * DI + gn] = sp;               // delta
                } else if (gn < 2 * DI) {
                    O1[(size_t)gm * DS + (gn - DI)] = v;         // B
                } else {
                    O2[(size_t)gm * DS + (gn - 2 * DI)] = v;     // C
                }
            } else {
                O0[(size_t)gm * NE + gn] = v;
            }
        }
    }
}

// ---------------------------------------------------------------------------
__global__ void conv_silu_kernel(const float* __restrict__ xi,
                                 const float* __restrict__ conv_w,
                                 const float* __restrict__ conv_b,
                                 float* __restrict__ u) {
    const int idx = blockIdx.x * blockDim.x + threadIdx.x;
    if (idx >= SEQ * DI) return;
    const int l = idx / DI;
    const int d = idx - l * DI;
    const float4 w = ((const float4*)conv_w)[d];
    float acc = conv_b[d];
    if (l >= 3) acc = fmaf(xi[(size_t)(l - 3) * DI + d], w.x, acc);
    if (l >= 2) acc = fmaf(xi[(size_t)(l - 2) * DI + d], w.y, acc);
    if (l >= 1) acc = fmaf(xi[(size_t)(l - 1) * DI + d], w.z, acc);
    acc = fmaf(xi[(size_t)l * DI + d], w.w, acc);
    u[idx] = acc * fast_sigmoid(acc);
}

// ---------------------------------------------------------------------------
// Phase A: chunk-local scan. ONE WAVE per block; block = (chunk k, d-group).
// Lane owns 24 states: 4 channels (dd=0..3) x 6 states (n = 6*lane + j).
// B/C loads are shared across the 4 channels.
// ---------------------------------------------------------------------------
__launch_bounds__(64)
__global__ void scanA_kernel(const float* __restrict__ delta,
                             const float* __restrict__ u,
                             const float* __restrict__ Bmat,
                             const float* __restrict__ Cmat,
                             const float* __restrict__ A_log,
                             float* __restrict__ ylocal,
                             float* __restrict__ hend,
                             float* __restrict__ Schunk) {
    const int k    = blockIdx.x;
    const int d0   = blockIdx.y * DG;
    const int lane = threadIdx.x;
    const int l0   = k * LC;
    const int dd   = lane >> 4;      // staging channel 0..3
    const int ls   = lane & 15;      // staging l 0..15 (two rounds)

    __shared__ float4 s_dt4[LC];     // dt per (l, dd)
    __shared__ float4 s_du4[LC];     // dt*u per (l, dd)
    __shared__ float  part[DG][LC];

    // stage dt, dt*u (each lane covers l = ls and ls+16 for channel dd)
    float dtk0, dtk1;
    {
        const float dt0 = delta[(size_t)(l0 + ls) * DI + d0 + dd];
        const float uu0 = u[(size_t)(l0 + ls) * DI + d0 + dd];
        const float dt1 = delta[(size_t)(l0 + ls + 16) * DI + d0 + dd];
        const float uu1 = u[(size_t)(l0 + ls + 16) * DI + d0 + dd];
        ((float*)&s_dt4[ls])[dd]      = dt0;
        ((float*)&s_du4[ls])[dd]      = dt0 * uu0;
        ((float*)&s_dt4[ls + 16])[dd] = dt1;
        ((float*)&s_du4[ls + 16])[dd] = dt1 * uu1;
        dtk0 = dt0; dtk1 = dt1;
    }

    // a[e][j] = -exp(A_log[d0+e][6*lane+j]) * log2(e)
    float a[DG][SN], h[DG][SN];
    #pragma unroll
    for (int e = 0; e < DG; ++e) {
        const float* ap = A_log + (size_t)(d0 + e) * DS + 6 * lane;
        #pragma unroll
        for (int j = 0; j < SN; ++j) {
            a[e][j] = -__expf(ap[j]) * LOG2E;
            h[e][j] = 0.0f;
        }
    }
    __syncthreads();

    const float* __restrict__ bp = Bmat + (size_t)l0 * DS + 6 * lane;
    const float* __restrict__ cp = Cmat + (size_t)l0 * DS + 6 * lane;

    #pragma unroll 2
    for (int l = 0; l < LC; ++l) {
        const float4 dt4 = s_dt4[l];
        const float4 du4 = s_du4[l];
        const float2 b0 = *(const float2*)(bp + (size_t)l * DS);
        const float2 b1 = *(const float2*)(bp + (size_t)l * DS + 2);
        const float2 b2 = *(const float2*)(bp + (size_t)l * DS + 4);
        const float2 c0 = *(const float2*)(cp + (size_t)l * DS);
        const float2 c1 = *(const float2*)(cp + (size_t)l * DS + 2);
        const float2 c2 = *(const float2*)(cp + (size_t)l * DS + 4);
        const float bb[SN] = {b0.x, b0.y, b1.x, b1.y, b2.x, b2.y};
        const float cc[SN] = {c0.x, c0.y, c1.x, c1.y, c2.x, c2.y};
        #pragma unroll
        for (int e = 0; e < DG; ++e) {
            const float dt = ((const float*)&dt4)[e];
            const float du = ((const float*)&du4)[e];
            float p = 0.0f;
            #pragma unroll
            for (int j = 0; j < SN; ++j) {
                h[e][j] = fmaf(EXP2F(dt * a[e][j]), h[e][j], du * bb[j]);
                p = fmaf(h[e][j], cc[j], p);
            }
            p = wave_reduce63(p);
            if (lane == 63) part[e][l] = p;
        }
    }

    // hend
    #pragma unroll
    for (int e = 0; e < DG; ++e) {
        float* hp = hend + (size_t)((d0 + e) * NC + k) * DS + 6 * lane;
        *(float2*)(hp + 0) = make_float2(h[e][0], h[e][1]);
        *(float2*)(hp + 2) = make_float2(h[e][2], h[e][3]);
        *(float2*)(hp + 4) = make_float2(h[e][4], h[e][5]);
    }
    // Schunk: row-reduce the staged dt's (each 16-lane row = one channel)
    {
        float s = dtk0 + dtk1;
        s = dpp_add<0x111>(s);
        s = dpp_add<0x112>(s);
        s = dpp_add<0x114>(s);
        s = dpp_add<0x118>(s);
        if (ls == 15) Schunk[(d0 + dd) * NC + k] = s;
    }
    __syncthreads();
    // ylocal
    ylocal[(size_t)(d0 + dd) * SEQ + l0 + ls]      = part[dd][ls];
    ylocal[(size_t)(d0 + dd) * SEQ + l0 + ls + 16] = part[dd][ls + 16];
}

// ---------------------------------------------------------------------------
// Phase B: cross-chunk combine; hend[d,k,:] becomes h_start for chunk k.
// ---------------------------------------------------------------------------
__launch_bounds__(DI)
__global__ void scanB_kernel(const float* __restrict__ A_log,
                             const float* __restrict__ Schunk,
                             float* __restrict__ hend) {
    const int d = blockIdx.x;
    const int n = threadIdx.x;
    const float a = -__expf(A_log[(size_t)d * DS + n]) * LOG2E;
    float H = 0.0f;
    #pragma unroll
    for (int k = 0; k < NC; ++k) {
        const float prev = H;
        const float dtot = EXP2F(a * Schunk[d * NC + k]);
        const float he   = hend[(size_t)(d * NC + k) * DS + n];
        H = fmaf(dtot, H, he);
        hend[(size_t)(d * NC + k) * DS + n] = prev;
    }
}

// ---------------------------------------------------------------------------
// Phase C: correction + gating. Same 4-channel x 6-state single-wave layout.
// ---------------------------------------------------------------------------
__launch_bounds__(64)
__global__ void scanC_kernel(const float* __restrict__ delta,
                             const float* __restrict__ u,
                             const float* __restrict__ Cmat,
                             const float* __restrict__ A_log,
                             const float* __restrict__ Dvec,
                             const float* __restrict__ sres,
                             const float* __restrict__ ylocal,
                             const float* __restrict__ hstart,
                             float* __restrict__ yfin) {
    const int k    = blockIdx.x;
    const int d0   = blockIdx.y * DG;
    const int lane = threadIdx.x;
    const int l0   = k * LC;
    const int dd   = lane >> 4;
    const int ls   = lane & 15;

    __shared__ float4 s_dt4[LC];
    __shared__ float  part[DG][LC];

    if (k > 0) {
        ((float*)&s_dt4[ls])[dd]      = delta[(size_t)(l0 + ls) * DI + d0 + dd];
        ((float*)&s_dt4[ls + 16])[dd] = delta[(size_t)(l0 + ls + 16) * DI + d0 + dd];

        float a[DG][SN], q[DG][SN];
        #pragma unroll
        for (int e = 0; e < DG; ++e) {
            const float* ap = A_log + (size_t)(d0 + e) * DS + 6 * lane;
            const float* hp = hstart + (size_t)((d0 + e) * NC + k) * DS + 6 * lane;
            #pragma unroll
            for (int j = 0; j < SN; ++j) {
                a[e][j] = -__expf(ap[j]) * LOG2E;
                q[e][j] = hp[j];
            }
        }
        __syncthreads();

        const float* __restrict__ cp = Cmat + (size_t)l0 * DS + 6 * lane;

        #pragma unroll 2
        for (int l = 0; l < LC; ++l) {
            const float4 dt4 = s_dt4[l];
            const float2 c0 = *(const float2*)(cp + (size_t)l * DS);
            const float2 c1 = *(const float2*)(cp + (size_t)l * DS + 2);
            const float2 c2 = *(const float2*)(cp + (size_t)l * DS + 4);
            const float cc[SN] = {c0.x, c0.y, c1.x, c1.y, c2.x, c2.y};
            #pragma unroll
            for (int e = 0; e < DG; ++e) {
                const float dt = ((const float*)&dt4)[e];
                float p = 0.0f;
                #pragma unroll
                for (int j = 0; j < SN; ++j) {
                    q[e][j] *= EXP2F(dt * a[e][j]);
                    p = fmaf(q[e][j], cc[j], p);
                }
                p = wave_reduce63(p);
                if (lane == 63) part[e][l] = p;
            }
        }
        __syncthreads();
    }

    // gating epilogue: lane covers (dd, ls) and (dd, ls+16)
    const float Dd = Dvec[d0 + dd];
    #pragma unroll
    for (int hh = 0; hh < 2; ++hh) {
        const int l = l0 + ls + hh * 16;
        float y = ylocal[(size_t)(d0 + dd) * SEQ + l];
        if (k > 0) y += part[dd][ls + hh * 16];
        const float uv = u[(size_t)l * DI + d0 + dd];
        const float sr = sres[(size_t)l * DI + d0 + dd];
        yfin[(size_t)l * DI + d0 + dd] = (y + uv * Dd) * sr;
    }
}

// ---------------------------------------------------------------------------
extern "C" void kernel_launch(void* const* d_in, const int* in_sizes, int n_in,
                              void* d_out, int out_size, void* d_ws, size_t ws_size,
                              hipStream_t stream) {
    const float* x      = (const float*)d_in[0];
    const float* W_in   = (const float*)d_in[1];
    const float* b_in   = (const float*)d_in[2];
    const float* conv_w = (const float*)d_in[3];
    const float* conv_b = (const float*)d_in[4];
    const float* W_xp   = (const float*)d_in[5];
    const float* W_dt   = (const float*)d_in[6];
    const float* A_log  = (const float*)d_in[7];
    const float* Dvec   = (const float*)d_in[8];
    const float* W_out  = (const float*)d_in[9];
    const float* b_out  = (const float*)d_in[10];
    float* out = (float*)d_out;

    float* ws = (float*)d_ws;
    const size_t LD = (size_t)SEQ * DI;   // 196608
    float* xi     = ws;                   // dead after conv -> reused as ylocal
    float* sres   = ws + LD;
    float* u      = ws + 2 * LD;
    float* Bm     = ws + 3 * LD;
    float* Cm     = ws + 4 * LD;
    float* delta  = ws + 5 * LD;
    float* yfin   = ws + 6 * LD;
    float* ylocal = xi;                   // alias: [DI][SEQ]
    float* hend   = ws + 7 * LD;                    // [DI][NC][DS]
    float* Schunk = hend + (size_t)DI * NC * DS;    // [DI][NC]
    float* Wd     = Schunk + (size_t)DI * NC;       // [DI][DI]

    prep_wd<<<DI, DI, 0, stream>>>(W_dt, W_xp, Wd);
    gemm_nt<0><<<dim3(12, 8), 256, 0, stream>>>(x, W_in, nullptr, b_in,
                                                xi, sres, nullptr, SEQ, 2 * DI, NE);
    conv_silu_kernel<<<(SEQ * DI + 255) / 256, 256, 0, stream>>>(xi, conv_w, conv_b, u);
    gemm_nt<1><<<dim3(18, 8), 256, 0, stream>>>(u, Wd, W_xp, nullptr,
                                                delta, Bm, Cm, SEQ, 3 * DI, DI);
    scanA_kernel<<<dim3(NC, DI / DG), 64, 0, stream>>>(delta, u, Bm, Cm, A_log,
                                                       ylocal, hend, Schunk);
    scanB_kernel<<<DI, DI, 0, stream>>>(A_log, Schunk, hend);
    scanC_kernel<<<dim3(NC, DI / DG), 64, 0, stream>>>(delta, u, Cm, A_log, Dvec, sres,
                                                       ylocal, hend, yfin);
    gemm_nt<2><<<dim3(3, 8), 256, 0, stream>>>(yfin, W_out, nullptr, b_out,
                                               out, nullptr, nullptr, SEQ, NE, DI);
}